// Round 2
// baseline (543.181 us; speedup 1.0000x reference)
//
#include <hip/hip_runtime.h>

#define D 64

// ---------------- rel kernel: R = rel_emb @ Wf^T ; rel_out = rel_emb @ Wrel^T
__global__ __launch_bounds__(64) void rel_kernel(
    const float* __restrict__ rel_emb,
    const float* __restrict__ W_f,
    const float* __restrict__ W_rel,
    float* __restrict__ R,
    float* __restrict__ rel_out,
    int n_rel) {
  int r = blockIdx.x;
  if (r >= n_rel) return;
  int j = threadIdx.x;  // 0..63 = output column
  float v = rel_emb[r * D + j];
  float accR = 0.f, accO = 0.f;
#pragma unroll 16
  for (int k = 0; k < D; ++k) {
    float a = __shfl(v, k);
    accR += a * W_f[j * D + k];
    accO += a * W_rel[j * D + k];
  }
  R[r * D + j] = accR;
  rel_out[r * D + j] = accO;
}

// ---------------- node kernel: out = nf @ Wself^T + bias ; X = nf @ Wf^T
// W in per-lane registers (lane j holds W[j][:]); row broadcast via
// wave-uniform-address global loads. Zero LDS traffic.
__global__ __launch_bounds__(256) void node_kernel(
    const float* __restrict__ nf,
    const float* __restrict__ W_self,
    const float* __restrict__ W_f,
    const float* __restrict__ bias,
    float* __restrict__ out,
    float* __restrict__ X,
    int n_nodes) {
  int lane = threadIdx.x & 63;

  // lane j caches row j of W_self and W_forward (row-major [out][in]).
  float4 ws[16], wf[16];
  const float4* Wsv = (const float4*)(W_self + lane * D);
  const float4* Wfv = (const float4*)(W_f + lane * D);
#pragma unroll
  for (int k = 0; k < 16; ++k) {
    ws[k] = Wsv[k];
    wf[k] = Wfv[k];
  }
  float b = bias[lane];

  int wave_id = (int)((blockIdx.x * blockDim.x + threadIdx.x) >> 6);
  int n_waves = (int)((gridDim.x * blockDim.x) >> 6);

  for (int row = wave_id; row < n_nodes; row += n_waves) {
    const float4* a = (const float4*)(nf + (size_t)row * D);
    float accS = 0.f, accF = 0.f;
#pragma unroll
    for (int k = 0; k < 16; ++k) {
      float4 av = a[k];  // wave-uniform address: single broadcast transaction
      accS += av.x * ws[k].x + av.y * ws[k].y + av.z * ws[k].z + av.w * ws[k].w;
      accF += av.x * wf[k].x + av.y * wf[k].y + av.z * wf[k].z + av.w * wf[k].w;
    }
    out[(size_t)row * D + lane] = accS + b;
    X[(size_t)row * D + lane] = accF;
  }
}

// ---------------- edge kernel: out[dst] += X[src] - R[etype]  (forward edges)
// 4 edges in flight per wave: 16 lanes x float4 per edge row.
__global__ __launch_bounds__(256) void edge_kernel(
    const int* __restrict__ src, const int* __restrict__ dst,
    const int* __restrict__ et, const int* __restrict__ dir,
    const float* __restrict__ X, const float* __restrict__ R,
    float* __restrict__ out, int n_edges) {
  int lane = threadIdx.x & 63;
  int sub = lane >> 4;   // edge group 0..3
  int l16 = lane & 15;   // lane within group
  long long wave_id = ((long long)blockIdx.x * blockDim.x + threadIdx.x) >> 6;
  long long n_waves = ((long long)gridDim.x * blockDim.x) >> 6;

  for (long long base = wave_id * 64; base < n_edges; base += n_waves * 64) {
    int e = (int)base + lane;
    int s_l = 0, d_l = 0, t_l = 0, dir_l = 1;
    if (e < n_edges) {
      s_l = src[e];  // coalesced: 64 consecutive edges per wave
      d_l = dst[e];
      t_l = et[e];
      dir_l = dir[e];
    }
    for (int i = 0; i < 64; i += 4) {
      int idx = i + sub;  // edge this 16-lane group handles
      int dir_i = __shfl(dir_l, idx);
      int s_i = __shfl(s_l, idx);
      int t_i = __shfl(t_l, idx);
      int d_i = __shfl(d_l, idx);
      bool active = (base + idx < n_edges) && (dir_i == 0);
      if (active) {
        float4 x = *(const float4*)(X + (size_t)s_i * D + l16 * 4);
        float4 r = *(const float4*)(R + (size_t)t_i * D + l16 * 4);
        float* o = out + (size_t)d_i * D + l16 * 4;
        atomicAdd(o + 0, x.x - r.x);
        atomicAdd(o + 1, x.y - r.y);
        atomicAdd(o + 2, x.z - r.z);
        atomicAdd(o + 3, x.w - r.w);
      }
    }
  }
}

extern "C" void kernel_launch(void* const* d_in, const int* in_sizes, int n_in,
                              void* d_out, int out_size, void* d_ws, size_t ws_size,
                              hipStream_t stream) {
  const float* node_feat = (const float*)d_in[0];
  const float* rel_emb   = (const float*)d_in[1];
  const int*   src       = (const int*)d_in[2];
  const int*   dst       = (const int*)d_in[3];
  const int*   etype     = (const int*)d_in[4];
  const int*   direction = (const int*)d_in[5];
  const float* W_self    = (const float*)d_in[6];
  const float* W_forward = (const float*)d_in[7];
  // d_in[8] = W_backward (unused: backward edges contribute zero)
  const float* W_rel     = (const float*)d_in[9];
  const float* bias      = (const float*)d_in[10];

  int n_nodes = in_sizes[0] / D;
  int n_rel   = in_sizes[1] / D;
  int n_edges = in_sizes[2];

  float* out     = (float*)d_out;                 // [n_nodes, 64]
  float* rel_out = out + (size_t)n_nodes * D;     // [n_rel, 64]

  float* X = (float*)d_ws;                        // [n_nodes, 64]
  float* R = X + (size_t)n_nodes * D;             // [n_rel, 64]

  // 1) R and rel_out (independent, tiny)
  rel_kernel<<<n_rel, 64, 0, stream>>>(rel_emb, W_forward, W_rel, R, rel_out, n_rel);

  // 2) out = nf@Ws^T + bias ; X = nf@Wf^T
  node_kernel<<<1024, 256, 0, stream>>>(node_feat, W_self, W_forward, bias,
                                        out, X, n_nodes);

  // 3) scatter-add forward edge messages
  edge_kernel<<<2048, 256, 0, stream>>>(src, dst, etype, direction, X, R, out,
                                        n_edges);
}